// Round 4
// baseline (702.789 us; speedup 1.0000x reference)
//
#include <hip/hip_runtime.h>
#include <cstdint>
#include <climits>

// Problem constants (fixed by setup_inputs)
constexpr int kB = 2;
constexpr int kN = 100;
constexpr int kH = 640;
constexpr int kW = 640;
constexpr int kHW = kH * kW;          // 409600
constexpr int kWORDS = kHW / 64;      // 6400 u64 words per mask
constexpr int kD = 384;
constexpr int kFH = 40;
constexpr int kFW = 40;
constexpr int kC = 80;
constexpr int kC1 = kC + 1;           // 81
constexpr int kTOPK = 40;
constexpr int kPairMax = kN * (kN - 1) / 2;  // 4950

constexpr float MASK_THRESH = 0.4f;
constexpr float SCORE_THRESH = 0.35f;
constexpr float SUPPRESS_IOU = 0.85f;

// Output layout (concatenated flat, reference return order)
constexpr size_t O_MASK = 0;
constexpr size_t O_CLS  = (size_t)kB * kN * kHW;          // 81,920,000
constexpr size_t O_BOX  = O_CLS + (size_t)kB * kN * kC1;  // +16,200
constexpr size_t O_EMB  = O_BOX + (size_t)kB * kN * 4;    // +800

// Native clang vector type — __builtin_nontemporal_store rejects the HIP
// float4 class type but accepts ext_vector_type.
typedef float floatx4 __attribute__((ext_vector_type(4)));
__device__ __forceinline__ void nt_store4(const float4& v, float4* p) {
    floatx4 t; t.x = v.x; t.y = v.y; t.z = v.z; t.w = v.w;
    __builtin_nontemporal_store(t, (floatx4*)p);
}

// Precise version (cold path: class_logits — 8.1K values)
__device__ __forceinline__ float logitf_(float p) {
    p = fminf(fmaxf(p, 1e-4f), 1.0f - 1e-4f);
    return logf(p) - log1pf(-p);
}

// Fast version (hot path: 32.8M mask-logit pixels). logit = ln(p/(1-p)).
// 1-p exact where it matters (Sterbenz); __fdividef 2.5 ulp; v_log_f32 ~1 ulp
// -> abs error < 1e-5 on a value of magnitude <= 9.21.
__device__ __forceinline__ float logit_fast(float p) {
    p = fminf(fmaxf(p, 1e-4f), 1.0f - 1e-4f);
    float r = __fdividef(p, 1.0f - p);
    return __log2f(r) * 0.69314718056f;
}

// ---------------------------------------------------------------------------
// K3f: stream -20 into the always-invalid slot region [kTOPK, kN) — count can
// never exceed kTOPK. Pure constant write, independent of everything: launch
// first. Nontemporal (never re-read). grid(1024, kB), block(256).
__global__ __launch_bounds__(256) void k3f_fill(float* __restrict__ out) {
    int b = blockIdx.y;
    float4* base = (float4*)(out + O_MASK + ((size_t)b * kN + kTOPK) * (size_t)kHW);
    const size_t n4 = (size_t)(kN - kTOPK) * kHW / 4;  // 6,144,000 float4/image
    float4 f = make_float4(-20.f, -20.f, -20.f, -20.f);
    for (size_t i = (size_t)blockIdx.x * 256 + threadIdx.x; i < n4;
         i += (size_t)gridDim.x * 256)
        nt_store4(f, base + i);
}

// ---------------------------------------------------------------------------
// K1: bit-pack thresholded masks (sorted order) + per-split area/bbox
// partials. grid(SPLIT=8, kN, kB), block(256). The stable descending-score
// rank sort is recomputed locally in LDS (O(100^2)/100 threads ≈ trivial) —
// no k0 kernel, no atomics, no init pass. float4 loads, 4 ballots/iter; bit
// order within words is a fixed permutation (k2 only ANDs+popcounts pairs).
// Slots with sorted score < SCORE_THRESH can never be kept or conflict-
// checked (sorted prefix property) — skip them entirely.
constexpr int kSPLIT = 8;
__global__ __launch_bounds__(256) void k1_pack(
    const float* __restrict__ masks, const float* __restrict__ scores,
    unsigned long long* __restrict__ packed, int* __restrict__ areaPart,
    int* __restrict__ bboxPart) {
    int b = blockIdx.z, slot = blockIdx.y;
    int t = threadIdx.x;
    __shared__ float sS[kN];
    __shared__ int sQ;
    __shared__ float sSc;
    if (t < kN) sS[t] = scores[b * kN + t];
    __syncthreads();
    if (t < kN) {
        float si = sS[t];
        int rank = 0;
        for (int j = 0; j < kN; ++j) {
            float sj = sS[j];
            if (sj > si || (sj == si && j < t)) rank++;
        }
        if (rank == slot) { sQ = t; sSc = si; }  // ranks are a permutation
    }
    __syncthreads();
    if (sSc < SCORE_THRESH) return;  // provably never kept / never paired
    int q = sQ;

    const float4* src = (const float4*)(masks + (size_t)(b * kN + q) * kHW);
    unsigned long long* dst = packed + (size_t)(b * kN + slot) * (size_t)kWORDS;
    int lane = t & 63;
    int wv = t >> 6;
    const int wordsPerBlock = kWORDS / kSPLIT;  // 800
    const int wordsPerWave = wordsPerBlock / 4; // 200
    int wbase = blockIdx.x * wordsPerBlock + wv * wordsPerWave;
    int pixBase = wbase * 64;

    int areaAcc = 0;
    int x1 = INT_MAX, x2 = INT_MIN, y1 = INT_MAX, y2 = INT_MIN;
#pragma unroll 2
    for (int i = 0; i < wordsPerWave / 4; ++i) {   // 50 float4 iterations
        int pix = pixBase + i * 256 + lane * 4;    // 4 consecutive pixels
        float4 v = src[pix >> 2];
        bool p0 = v.x > MASK_THRESH, p1 = v.y > MASK_THRESH;
        bool p2 = v.z > MASK_THRESH, p3 = v.w > MASK_THRESH;
        unsigned long long b0 = __ballot(p0);
        unsigned long long b1 = __ballot(p1);
        unsigned long long b2 = __ballot(p2);
        unsigned long long b3 = __ballot(p3);
        if (lane == 0) {
            dst[wbase + 4 * i + 0] = b0;
            dst[wbase + 4 * i + 1] = b1;
            dst[wbase + 4 * i + 2] = b2;
            dst[wbase + 4 * i + 3] = b3;
        }
        int cnt = (int)p0 + (int)p1 + (int)p2 + (int)p3;
        areaAcc += cnt;
        if (cnt) {
            // 640 % 4 == 0 → the 4 pixels never straddle a row boundary
            int row  = pix / kW;
            int col0 = pix - row * kW;
            int lo = p0 ? 0 : (p1 ? 1 : (p2 ? 2 : 3));
            int hi = p3 ? 3 : (p2 ? 2 : (p1 ? 1 : 0));
            x1 = min(x1, col0 + lo); x2 = max(x2, col0 + hi);
            y1 = min(y1, row);       y2 = max(y2, row);
        }
    }
    // wave-level reduce
#pragma unroll
    for (int off = 32; off > 0; off >>= 1) {
        areaAcc += __shfl_down(areaAcc, off);
        x1 = min(x1, __shfl_down(x1, off));
        x2 = max(x2, __shfl_down(x2, off));
        y1 = min(y1, __shfl_down(y1, off));
        y2 = max(y2, __shfl_down(y2, off));
    }
    __shared__ int sA[4], sx1[4], sx2[4], sy1[4], sy2[4];
    if (lane == 0) { sA[wv] = areaAcc; sx1[wv] = x1; sx2[wv] = x2; sy1[wv] = y1; sy2[wv] = y2; }
    __syncthreads();
    if (t == 0) {
        int A   = sA[0] + sA[1] + sA[2] + sA[3];
        int bx1 = min(min(sx1[0], sx1[1]), min(sx1[2], sx1[3]));
        int bx2 = max(max(sx2[0], sx2[1]), max(sx2[2], sx2[3]));
        int by1 = min(min(sy1[0], sy1[1]), min(sy1[2], sy1[3]));
        int by2 = max(max(sy2[0], sy2[1]), max(sy2[2], sy2[3]));
        // plain partial stores — consumer (k2) reduces the 8 parts
        areaPart[(b * kN + slot) * kSPLIT + blockIdx.x] = A;
        int* bp = bboxPart + ((b * kN + slot) * kSPLIT + blockIdx.x) * 4;
        bp[0] = bx1; bp[1] = bx2; bp[2] = by1; bp[3] = by2;
    }
}

// ---------------------------------------------------------------------------
// K2: fused NMS — pair enumeration + IoU conflict bits + sequential greedy +
// class_logits + boxes, one block of 1024 per image, everything LDS-resident.
// Pair intersections: one wave per pair (64 lanes × 100 u64 words, coalesced
// 512B/instr, ~26 pairs expected). Conflict bits in u32[4]/row via LDS
// atomicOr. grid(kB), block(1024).
__global__ __launch_bounds__(1024) void k2_nms_clsbox(
    const float* __restrict__ scores, const int* __restrict__ labels,
    const unsigned long long* __restrict__ packed,
    const int* __restrict__ areaPart, const int* __restrict__ bboxPart,
    int* __restrict__ src_q, int* __restrict__ countArr,
    float* __restrict__ out) {
    int b = blockIdx.x;
    int t = threadIdx.x;
    __shared__ float sRaw[kN];
    __shared__ int   lRaw[kN];
    __shared__ float ssort[kN];
    __shared__ int   lsort[kN];
    __shared__ int   ordL[kN];
    __shared__ int   areaS[kN];
    __shared__ unsigned int conf[kN][4];
    __shared__ int   pairL[kPairMax];
    __shared__ int   pairN;
    __shared__ int   ksL[kN];
    __shared__ int   cntS;

    if (t < kN) { sRaw[t] = scores[b * kN + t]; lRaw[t] = labels[b * kN + t]; }
    if (t == 0) pairN = 0;
    for (int e = t; e < kN * 4; e += 1024) conf[e >> 2][e & 3] = 0u;
    __syncthreads();
    if (t < kN) {
        float si = sRaw[t];
        int rank = 0;
        for (int j = 0; j < kN; ++j) {
            float sj = sRaw[j];
            if (sj > si || (sj == si && j < t)) rank++;
        }
        ssort[rank] = si; lsort[rank] = lRaw[t]; ordL[rank] = t;
    }
    __syncthreads();
    // area reduce (only above-thresh slots have valid partials)
    if (t < kN) {
        int a = 0;
        if (ssort[t] >= SCORE_THRESH)
            for (int p = 0; p < kSPLIT; ++p) a += areaPart[(b * kN + t) * kSPLIT + p];
        areaS[t] = a;
    }
    // candidate pairs (j < i, same label, score[i] >= thresh → both >= thresh)
    for (int idx = t; idx < kN * kN; idx += 1024) {
        int i = idx / kN, j = idx - i * kN;
        if (j < i && lsort[i] == lsort[j] && ssort[i] >= SCORE_THRESH) {
            int pos = atomicAdd(&pairN, 1);
            pairL[pos] = (i << 16) | j;
        }
    }
    __syncthreads();
    int lane = t & 63, wv = t >> 6;
    int np = pairN;
    for (int p = wv; p < np; p += 16) {
        int pr = pairL[p];
        int i = pr >> 16, j = pr & 0xffff;
        const unsigned long long* pi = packed + (size_t)(b * kN + i) * kWORDS;
        const unsigned long long* pj = packed + (size_t)(b * kN + j) * kWORDS;
        int acc = 0;
        for (int w = lane; w < kWORDS; w += 64)
            acc += __popcll(pi[w] & pj[w]);
#pragma unroll
        for (int off = 32; off > 0; off >>= 1) acc += __shfl_down(acc, off);
        if (lane == 0) {
            float inter = (float)acc;
            float un = fmaxf((float)areaS[i] + (float)areaS[j] - inter, 1.0f);
            if (inter / un >= SUPPRESS_IOU)
                atomicOr(&conf[i][j >> 5], 1u << (j & 31));
        }
    }
    __syncthreads();
    if (t == 0) {
        unsigned int kept[4] = {0u, 0u, 0u, 0u};
        bool stopped = false;
        int count = 0;
        for (int i = 0; i < kN; ++i) {
            if (ssort[i] < SCORE_THRESH) stopped = true;
            unsigned int cl = (conf[i][0] & kept[0]) | (conf[i][1] & kept[1]) |
                              (conf[i][2] & kept[2]) | (conf[i][3] & kept[3]);
            bool take = (!stopped) && (cl == 0u);
            if (take) {
                kept[i >> 5] |= 1u << (i & 31);
                src_q[b * kN + count] = ordL[i];
                ksL[count] = i;
                count++;
                if (count >= kTOPK) stopped = true;
            }
        }
        countArr[b] = count;
        cntS = count;
        for (int s = count; s < kN; ++s) { src_q[b * kN + s] = -1; ksL[s] = -1; }
    }
    __syncthreads();
    int count = cntS;

    // class_logits
    for (int e = t; e < kN * kC1; e += 1024) {
        int slot = e / kC1, c = e - slot * kC1;
        float val = -10.0f;
        if (slot < count) {
            int s2 = ksL[slot];
            int lab = min(max(lsort[s2], 0), kC - 1);
            float scv = fminf(fmaxf(ssort[s2], 0.f), 1.f);
            if (c == lab) val = logitf_(scv);
            else if (c == kC1 - 1) val = 0.0f;
        }
        out[O_CLS + (size_t)b * kN * kC1 + e] = val;
    }
    // boxes (reduce the 8 bbox partials; kept ⊂ above-thresh so partials valid)
    if (t < kN) {
        int slot = t;
        float bx[4] = {0.f, 0.f, 0.f, 0.f};
        if (slot < count) {
            int s2 = ksL[slot];
            if (areaS[s2] > 0) {
                int x1 = INT_MAX, x2 = INT_MIN, y1 = INT_MAX, y2 = INT_MIN;
                for (int p = 0; p < kSPLIT; ++p) {
                    const int* bp = bboxPart + ((b * kN + s2) * kSPLIT + p) * 4;
                    x1 = min(x1, bp[0]); x2 = max(x2, bp[1]);
                    y1 = min(y1, bp[2]); y2 = max(y2, bp[3]);
                }
                float fx1 = (float)x1, fx2 = (float)x2;
                float fy1 = (float)y1, fy2 = (float)y2;
                bx[0] = fminf(fmaxf((fx1 + fx2) * 0.5f / kW, 0.f), 1.f);
                bx[1] = fminf(fmaxf((fy1 + fy2) * 0.5f / kH, 0.f), 1.f);
                bx[2] = fminf(fmaxf(fmaxf(fx2 - fx1, 0.f) / kW, 0.f), 1.f);
                bx[3] = fminf(fmaxf(fmaxf(fy2 - fy1, 0.f) / kH, 0.f), 1.f);
            }
        }
        for (int c4 = 0; c4 < 4; ++c4)
            out[O_BOX + (size_t)(b * kN + slot) * 4 + c4] = bx[c4];
    }
}

// ---------------------------------------------------------------------------
// K3: mask_logits + fused x-resize, kept-candidate slots only (< kTOPK).
// grid(kH/4, kTOPK, kB), block(256): one wave per mask row. Kept slots: read
// row once (float4 — L3-hits from k1's pass), write logits nontemporal, stage
// clipped row in padded LDS (col + col>>5 breaks the bank conflict), lanes
// 0..39 produce the x-resize outputs (identical tap weights/order). Slots in
// [count,kTOPK): constant -20 nt fill.
__global__ __launch_bounds__(256) void k3_logits_resizex(
    const float* __restrict__ masks, const int* __restrict__ src_q,
    float* __restrict__ out, float* __restrict__ S1) {
    int b = blockIdx.z, slot = blockIdx.y;
    int q = src_q[b * kN + slot];
    int lane = threadIdx.x & 63, wv = threadIdx.x >> 6;
    int y = blockIdx.x * 4 + wv;
    float4* dst = (float4*)(out + O_MASK + (size_t)(b * kN + slot) * kHW) + (size_t)y * 160;

    if (q < 0) {
        float4 f = make_float4(-20.f, -20.f, -20.f, -20.f);
        nt_store4(f, dst + lane);
        nt_store4(f, dst + 64 + lane);
        if (lane < 32) nt_store4(f, dst + 128 + lane);
        return;
    }

    __shared__ float rbuf[4][660];  // 640 + 20 pad floats per row
    const float4* src = (const float4*)(masks + (size_t)(b * kN + q) * kHW) + (size_t)y * 160;
#pragma unroll
    for (int i = 0; i < 3; ++i) {
        int idx = i * 64 + lane;
        if (idx < 160) {
            float4 m = src[idx];
            float4 o;
            o.x = logit_fast(m.x); o.y = logit_fast(m.y);
            o.z = logit_fast(m.z); o.w = logit_fast(m.w);
            nt_store4(o, dst + idx);
            int col = idx * 4;
            int pad = col >> 5;  // (col+c)>>5 == col>>5 for c in 0..3 (col%4==0)
            rbuf[wv][col + pad + 0] = fminf(fmaxf(m.x, 0.f), 1.f);
            rbuf[wv][col + pad + 1] = fminf(fmaxf(m.y, 0.f), 1.f);
            rbuf[wv][col + pad + 2] = fminf(fmaxf(m.z, 0.f), 1.f);
            rbuf[wv][col + pad + 3] = fminf(fmaxf(m.w, 0.f), 1.f);
        }
    }
    __syncthreads();
    if (lane < kFW) {
        int ox = lane;
        float c = 16.0f * ox + 7.5f;
        float s = 0.f;
#pragma unroll
        for (int tap = 0; tap < 32; ++tap) {
            int j = 16 * ox - 8 + tap;
            if (j >= 0 && j < kW) {
                float w = 1.0f - fabsf((float)j - c) * (1.0f / 16.0f);
                s += w * rbuf[wv][j + (j >> 5)];
            }
        }
        float rs = (ox == 0 || ox == kFW - 1) ? (1.0f / 14.0f) : (1.0f / 16.0f);
        S1[((size_t)(b * kTOPK + slot) * kH + y) * kFW + ox] = s * rs;
    }
}

// ---------------------------------------------------------------------------
// K9: fused y-resize + denom + mask-pooled features + L2-normalize (was
// k6+k7+k8). grid(kN, kB), block(512): one block per output slot. Invalid
// slots just zero 384 floats. Valid: msmall (1600) into LDS with identical
// tap order, denom tree-reduce, then 8 waves × 48 rounds of coalesced
// wave-dots against feat rows (L2-resident), then norm over d in-block.
__global__ __launch_bounds__(512) void k9_pool_embs(
    const float* __restrict__ S1, const float* __restrict__ feat,
    const int* __restrict__ countArr, float* __restrict__ out) {
    int slot = blockIdx.x, b = blockIdx.y;
    int t = threadIdx.x;
    int count = countArr[b];
    float* dst = out + O_EMB + (size_t)(b * kN + slot) * kD;
    if (slot >= count) {
        if (t < kD) dst[t] = 0.f;
        return;
    }
    __shared__ float ms[kFH * kFW];   // 1600
    __shared__ float pld[kD];         // 384
    __shared__ float red[512];
    const float* src = S1 + (size_t)(b * kTOPK + slot) * kH * kFW;
    float tot = 0.f;
    for (int e = t; e < kFH * kFW; e += 512) {
        int oy = e / kFW, ox = e - oy * kFW;
        float c = 16.0f * oy + 7.5f;
        int j0 = max(0, 16 * oy - 8), j1 = min(kH - 1, 16 * oy + 23);
        float s = 0.f;
        for (int j = j0; j <= j1; ++j) {
            float w = 1.0f - fabsf((float)j - c) * (1.0f / 16.0f);
            s += w * src[j * kFW + ox];
        }
        float rs = (oy == 0 || oy == kFH - 1) ? (1.0f / 14.0f) : (1.0f / 16.0f);
        s *= rs;
        ms[e] = s;
        tot += s;
    }
    red[t] = tot;
    __syncthreads();
    for (int st = 256; st > 0; st >>= 1) {
        if (t < st) red[t] += red[t + st];
        __syncthreads();
    }
    float denomC = fmaxf(red[0], 1e-6f);   // all threads read before red reuse

    int lane = t & 63, wv = t >> 6;
    for (int d = wv; d < kD; d += 8) {
        const float* fp = feat + ((size_t)b * kD + d) * (kFH * kFW);
        float acc = 0.f;
#pragma unroll
        for (int r = 0; r < 25; ++r) acc += fp[r * 64 + lane] * ms[r * 64 + lane];
#pragma unroll
        for (int off = 32; off > 0; off >>= 1) acc += __shfl_down(acc, off);
        if (lane == 0) pld[d] = acc / denomC;
    }
    __syncthreads();
    float ss = 0.f;
    if (t < kD) { float v = pld[t]; ss = v * v; }
    red[t] = ss;
    __syncthreads();
    for (int st = 256; st > 0; st >>= 1) {
        if (t < st) red[t] += red[t + st];
        __syncthreads();
    }
    float norm = fmaxf(sqrtf(red[0]), 1e-12f);
    if (t < kD) dst[t] = pld[t] / norm;
}

// ---------------------------------------------------------------------------
extern "C" void kernel_launch(void* const* d_in, const int* in_sizes, int n_in,
                              void* d_out, int out_size, void* d_ws, size_t ws_size,
                              hipStream_t stream) {
    const float* masks  = (const float*)d_in[0];
    const int*   labels = (const int*)d_in[1];
    const float* scores = (const float*)d_in[2];
    const float* feat   = (const float*)d_in[3];
    // d_in[4] = class_count (device scalar) — fixed at 80 per problem shape.
    float* out = (float*)d_out;

    // Workspace carve-up (~18.5 MB total)
    char* ws = (char*)d_ws;
    auto take = [&](size_t bytes) { char* p = ws; ws += (bytes + 255) & ~(size_t)255; return p; };
    unsigned long long* packed = (unsigned long long*)take((size_t)kB * kN * kWORDS * 8);
    float* S1      = (float*)take((size_t)kB * kTOPK * kH * kFW * 4);
    int* areaPart  = (int*)take((size_t)kB * kN * kSPLIT * 4);
    int* bboxPart  = (int*)take((size_t)kB * kN * kSPLIT * 4 * 4);
    int* src_q     = (int*)take((size_t)kB * kN * 4);
    int* countArr  = (int*)take((size_t)kB * 4);

    k3f_fill<<<dim3(1024, kB), dim3(256), 0, stream>>>(out);
    k1_pack<<<dim3(kSPLIT, kN, kB), dim3(256), 0, stream>>>(masks, scores, packed,
                                                            areaPart, bboxPart);
    k2_nms_clsbox<<<dim3(kB), dim3(1024), 0, stream>>>(scores, labels, packed,
                                                       areaPart, bboxPart, src_q,
                                                       countArr, out);
    k3_logits_resizex<<<dim3(kH / 4, kTOPK, kB), dim3(256), 0, stream>>>(masks, src_q,
                                                                         out, S1);
    k9_pool_embs<<<dim3(kN, kB), dim3(512), 0, stream>>>(S1, feat, countArr, out);
}